// Round 5
// baseline (699.521 us; speedup 1.0000x reference)
//
#include <hip/hip_runtime.h>
#include <hip/hip_bf16.h>
#include <math.h>

#define TOKENS 16384
#define DIM 4096
#define NEXP 64
#define TOPK 8
#define FILTER_R 0.62f
#define LOAD_LR 0.001f
#define EPS_GAP 1e-4f     // ~160 sigma of fp32 4-chain accum error (RMS ~6e-7)

#define TM 8              // tokens per wave
#define WAVES 4           // waves per block -> 32 tokens/block, 512 blocks
#define TB (TM * WAVES)   // 32 tokens per block
#define BK 128            // K-chunk (floats); per-wave tile = 8*128*4 = 4KB
#define NCHUNK (DIM / BK) // 32

// ---------------------------------------------------------------------------
// ws layout: [0, DIM*NEXP*4) = Wt4 transposed weights (1 MB)
//            [DIM*NEXP*4, +256) = histogram (64 ints)
// ---------------------------------------------------------------------------

// Transpose W[E][K] row-major into Wt4: element (k,e) at ((k>>2)*256 + e*4 + (k&3))
// so a wave (lane=expert) loads float4 = k..k+3 for its expert, 1KB coalesced.
__global__ void wt_transpose_kernel(const float* __restrict__ W,
                                    float* __restrict__ wt4,
                                    int* __restrict__ hist) {
    int tid = blockIdx.x * blockDim.x + threadIdx.x;   // 0 .. DIM*NEXP-1
    if (blockIdx.x == 0 && threadIdx.x < NEXP) hist[threadIdx.x] = 0;
    int e = tid >> 12;        // / DIM
    int k = tid & (DIM - 1);
    float v = W[tid];
    wt4[((k >> 2) << 8) + (e << 2) + (k & 3)] = v;
}

__global__ __launch_bounds__(256) void router_kernel(
    const float* __restrict__ x,
    const float* __restrict__ b,
    const float* __restrict__ bi,
    const float* __restrict__ rand_u,
    const float4* __restrict__ wt4,
    float* __restrict__ out,          // [0,131072) router_output, [131072,262144) indices-as-float
    int* __restrict__ hist_g) {
    // per-wave PRIVATE double-buffered x tile: no cross-wave sharing -> the
    // K-loop needs NO __syncthreads (barrier would drain vmcnt and kill the
    // load/compute overlap -- that was R4's failure).
    __shared__ float xbuf[WAVES][2][TM][BK];   // 32 KB
    __shared__ int lds_hist[NEXP];

    const int lane = threadIdx.x & 63;
    const int wave = __builtin_amdgcn_readfirstlane(threadIdx.x >> 6);
    if (threadIdx.x < NEXP) lds_hist[threadIdx.x] = 0;
    __syncthreads();                 // lds_hist visible; only barrier before epilogue

    const int t0 = blockIdx.x * TB + wave * TM;
    const int r_hi = lane >> 5;            // row parity within a load
    const int col  = (lane & 31) * 4;      // float column within a row

    // fp32 accumulators, 4 independent chains per (token, expert=lane)
    float4 a4[TM];
#pragma unroll
    for (int t = 0; t < TM; ++t) a4[t] = make_float4(0.f, 0.f, 0.f, 0.f);

    float4 st[4];   // staging regs: load i covers rows 2i,2i+1 of the tile

    // chunk 0: load + write LDS
#pragma unroll
    for (int i = 0; i < 4; ++i)
        st[i] = *(const float4*)(x + (size_t)(t0 + 2 * i + r_hi) * DIM + col);
#pragma unroll
    for (int i = 0; i < 4; ++i)
        *(float4*)&xbuf[wave][0][2 * i + r_hi][col] = st[i];

    for (int c = 0; c < NCHUNK; ++c) {
        const int buf = c & 1;
        // T14 issue-early: global loads for chunk c+1 into regs (in flight
        // across the whole compute phase; consumed by ds_write afterwards).
        if (c + 1 < NCHUNK) {
#pragma unroll
            for (int i = 0; i < 4; ++i)
                st[i] = *(const float4*)(x + (size_t)(t0 + 2 * i + r_hi) * DIM
                                           + (c + 1) * BK + col);
        }

        // compute chunk c: W per-lane from global (L1/L2), x via uniform
        // ds_read_b128 broadcast (conflict-free)
        const float4* wrow = wt4 + (size_t)c * (BK / 4) * 64 + lane;
#pragma unroll 4
        for (int k4 = 0; k4 < BK / 4; ++k4) {
            float4 wv = wrow[k4 * 64];
#pragma unroll
            for (int t = 0; t < TM; ++t) {
                float4 xv = *(const float4*)&xbuf[wave][buf][t][k4 * 4];
                a4[t].x = fmaf(xv.x, wv.x, a4[t].x);
                a4[t].y = fmaf(xv.y, wv.y, a4[t].y);
                a4[t].z = fmaf(xv.z, wv.z, a4[t].z);
                a4[t].w = fmaf(xv.w, wv.w, a4[t].w);
            }
        }

        // write-late: stage chunk c+1 into the other buffer (vmcnt wait lands
        // here, after compute -- loads had the whole chunk to complete)
        if (c + 1 < NCHUNK) {
#pragma unroll
            for (int i = 0; i < 4; ++i)
                *(float4*)&xbuf[wave][buf ^ 1][2 * i + r_hi][col] = st[i];
        }
    }

    const float b_lane  = b[lane];
    const float bi_lane = bi[lane];

    for (int t = 0; t < TM; ++t) {
        // unbiased logit (fp32) for (token t, expert=lane)
        const float vub = ((a4[t].x + a4[t].y) + (a4[t].z + a4[t].w)) + b_lane;
        float cur = vub + bi_lane;            // biased logit for selection

        float selv  = -INFINITY;              // lane j (0..8): biased value of j-th pick
        int   selidx = 0;                     // lane j: expert index of j-th pick

        // top-(TOPK+1) selection so we can gap-check the 8/9 boundary too
#pragma unroll
        for (int j = 0; j <= TOPK; ++j) {
            float bv = cur;
            int   bidx = lane;
#pragma unroll
            for (int s = 1; s < 64; s <<= 1) {
                float ov = __shfl_xor(bv, s, 64);
                int   oi = __shfl_xor(bidx, s, 64);
                bool take = (ov > bv) || (ov == bv && oi < bidx);
                if (take) { bv = ov; bidx = oi; }
            }
            if (lane == j) { selv = bv; selidx = bidx; }
            if (lane == bidx) cur = -INFINITY;
        }

        // lane j (0..7) gathers the UNBIASED logit of its pick
        float out_logit = __shfl(vub, selidx, 64);
        int   out_idx   = selidx;

        // gap check: selv on lanes 0..8 is descending; any adjacent gap < EPS
        // means fp32 rounding could have misordered -> recompute exactly.
        float nxtv = __shfl_down(selv, 1, 64);
        bool  bad  = (lane < TOPK) && (selv - nxtv < EPS_GAP);
        if (__any(bad)) {
            // f64 recompute of this token's logits (exact products, ~1e-14
            // accum err). Rare (~handful of tokens in 16384) -> slow loads OK.
            const float4* xrow = (const float4*)(x + (size_t)(t0 + t) * DIM);
            double d0 = 0.0, d1 = 0.0;
            for (int k4 = 0; k4 < DIM / 4; ++k4) {
                float4 wv = wt4[k4 * 64 + lane];
                float4 xv = xrow[k4];
                d0 = fma((double)xv.x, (double)wv.x, d0);
                d1 = fma((double)xv.y, (double)wv.y, d1);
                d0 = fma((double)xv.z, (double)wv.z, d0);
                d1 = fma((double)xv.w, (double)wv.w, d1);
            }
            const double dvub = (d0 + d1) + (double)b_lane;
            const float  vubf = (float)dvub;
            double dcur = dvub + (double)bi_lane;
#pragma unroll
            for (int j = 0; j < TOPK; ++j) {
                double bv = dcur;
                int    bidx = lane;
#pragma unroll
                for (int s = 1; s < 64; s <<= 1) {
                    double ov = __shfl_xor(bv, s, 64);
                    int    oi = __shfl_xor(bidx, s, 64);
                    bool take = (ov > bv) || (ov == bv && oi < bidx);
                    if (take) { bv = ov; bidx = oi; }
                }
                float wub = __shfl(vubf, bidx, 64);
                if (lane == j) { out_logit = wub; out_idx = bidx; }
                if (lane == bidx) dcur = -(double)INFINITY;
            }
        }

        // softmax over the 8 selected (lanes 0..7); xor masks 1,2,4 stay in 8-groups
        float sv = (lane < TOPK) ? out_logit : -INFINITY;
        float m = sv;
        m = fmaxf(m, __shfl_xor(m, 1, 64));
        m = fmaxf(m, __shfl_xor(m, 2, 64));
        m = fmaxf(m, __shfl_xor(m, 4, 64));
        float e = (lane < TOPK) ? expf(sv - m) : 0.f;
        float ssum = e;
        ssum += __shfl_xor(ssum, 1, 64);
        ssum += __shfl_xor(ssum, 2, 64);
        ssum += __shfl_xor(ssum, 4, 64);

        const int tt = t0 + t;
        if (lane < TOPK) {
            float p = e / ssum;
            float r = rand_u[tt * TOPK + lane];
            out[tt * TOPK + lane] = (r > FILTER_R) ? p : 0.f;
            out[TOKENS * TOPK + tt * TOPK + lane] = (float)out_idx;
            atomicAdd(&lds_hist[out_idx], 1);
        }
    }

    __syncthreads();
    if (threadIdx.x < NEXP) atomicAdd(&hist_g[threadIdx.x], lds_hist[threadIdx.x]);
}

__global__ void bias_update_kernel(const float* __restrict__ bi,
                                   const int* __restrict__ hist,
                                   float* __restrict__ out_bi) {
    int e = threadIdx.x;
    float c_avg = (float)TOKENS / (float)NEXP;     // 256
    float e_i = c_avg - (float)hist[e];
    float s = (e_i > 0.f) ? 1.f : ((e_i < 0.f) ? -1.f : 0.f);
    out_bi[e] = bi[e] + LOAD_LR * s;
}

extern "C" void kernel_launch(void* const* d_in, const int* in_sizes, int n_in,
                              void* d_out, int out_size, void* d_ws, size_t ws_size,
                              hipStream_t stream) {
    const float* x      = (const float*)d_in[0];
    const float* W      = (const float*)d_in[1];
    const float* b      = (const float*)d_in[2];
    const float* bi     = (const float*)d_in[3];
    const float* rand_u = (const float*)d_in[4];

    float* out  = (float*)d_out;
    float* wt4  = (float*)d_ws;
    int*   hist = (int*)((char*)d_ws + (size_t)DIM * NEXP * sizeof(float));

    // 1) transpose W for coalesced lane=expert loads; also zeroes histogram
    wt_transpose_kernel<<<(DIM * NEXP) / 256, 256, 0, stream>>>(W, wt4, hist);

    // 2) fused logits (wave-private LDS staging, barrier-free K-loop,
    //    fp32 + rare exact f64 fallback) + top-k + softmax + hist
    router_kernel<<<TOKENS / TB, 256, 0, stream>>>(
        x, b, bi, rand_u, (const float4*)wt4, out, hist);

    // 3) load-balance bias update -> out[262144..262208)
    bias_update_kernel<<<1, NEXP, 0, stream>>>(bi, hist, out + 2 * TOKENS * TOPK);
}

// Round 6
// 335.544 us; speedup vs baseline: 2.0847x; 2.0847x over previous
//
#include <hip/hip_runtime.h>
#include <hip/hip_bf16.h>
#include <math.h>

#define TOKENS 16384
#define DIM 4096
#define NEXP 64
#define TOPK 8
#define FILTER_R 0.62f
#define LOAD_LR 0.001f
#define EPS_GAP 2e-5f     // fp32 4-chain accum RMS err ~6e-7; flips need gap<1e-5

#define TM 8              // tokens per wave
#define WAVES 4           // waves per block -> 32 tokens/block, 512 blocks
#define TB (TM * WAVES)
#define NG (DIM / 32)     // 128 k-groups; each group = 8 k4 = 32 floats/row

// ws: [0, DIM*NEXP*4) = Wt4 transposed weights (1 MB); then 64-int histogram.

// Wt4: element (k,e) at float index (k>>2)*256 + e*4 + (k&3); as float4: (k>>2)*64+e.
__global__ void wt_transpose_kernel(const float* __restrict__ W,
                                    float* __restrict__ wt4,
                                    int* __restrict__ hist) {
    int tid = blockIdx.x * blockDim.x + threadIdx.x;
    if (blockIdx.x == 0 && threadIdx.x < NEXP) hist[threadIdx.x] = 0;
    int e = tid >> 12;
    int k = tid & (DIM - 1);
    wt4[((k >> 2) << 8) + (e << 2) + (k & 3)] = W[tid];
}

__device__ __forceinline__ float rdlane(float v, int l) {
    return __uint_as_float(__builtin_amdgcn_readlane(__float_as_uint(v), l));
}

__global__ __launch_bounds__(256, 2) void router_kernel(
    const float* __restrict__ x,
    const float* __restrict__ b,
    const float* __restrict__ bi,
    const float* __restrict__ rand_u,
    const float4* __restrict__ wt4,
    float* __restrict__ out,          // [0,131072) probs, [131072,262144) indices-as-float
    int* __restrict__ hist_g) {
    __shared__ int lds_hist[NEXP];

    const int lane = threadIdx.x & 63;
    const int wave = __builtin_amdgcn_readfirstlane(threadIdx.x >> 6);
    if (threadIdx.x < NEXP) lds_hist[threadIdx.x] = 0;
    __syncthreads();

    const int t0 = blockIdx.x * TB + wave * TM;
    const int lrow = lane >> 3;       // token row (0..7) this lane loads
    const int lk4  = lane & 7;        // k4 offset within the group

    // fp32 accumulators, 4 independent chains per (token, expert=lane)
    float4 a4[TM];
#pragma unroll
    for (int t = 0; t < TM; ++t) a4[t] = make_float4(0.f, 0.f, 0.f, 0.f);

    // per-lane x pointer: VECTOR loads (8 x 128B coalesced segments / instr),
    // double-buffered in registers, deep vmcnt pipeline. No scalar loads
    // (R2/R3 killer), no LDS round-trip (R4/R5 killer).
    const float* xbase = x + (size_t)(t0 + lrow) * DIM + lk4 * 4;
    float4 cur = *(const float4*)xbase;

    for (int g = 0; g < NG; ++g) {
        const int gn = (g + 1) & (NG - 1);          // last iter re-reads g0 (discarded)
        float4 nxt = *(const float4*)(xbase + gn * 32);
        const float4* wrow = wt4 + (size_t)g * 8 * 64 + lane;
#pragma unroll
        for (int j = 0; j < 8; ++j) {
            float4 wv = wrow[j * 64];               // per-lane, L1/L2-resident
#pragma unroll
            for (int t = 0; t < TM; ++t) {
                const int sl = t * 8 + j;           // compile-time lane
                a4[t].x = fmaf(rdlane(cur.x, sl), wv.x, a4[t].x);
                a4[t].y = fmaf(rdlane(cur.y, sl), wv.y, a4[t].y);
                a4[t].z = fmaf(rdlane(cur.z, sl), wv.z, a4[t].z);
                a4[t].w = fmaf(rdlane(cur.w, sl), wv.w, a4[t].w);
            }
        }
        cur = nxt;
    }

    const float b_lane  = b[lane];
    const float bi_lane = bi[lane];

    for (int t = 0; t < TM; ++t) {
        const float vub = ((a4[t].x + a4[t].y) + (a4[t].z + a4[t].w)) + b_lane;
        float cur_l = vub + bi_lane;          // biased logit for selection

        float selv  = -INFINITY;              // lane j (0..8): biased value of j-th pick
        int   selidx = 0;

        // top-(TOPK+1) so the 8/9 boundary is gap-checked too
#pragma unroll
        for (int j = 0; j <= TOPK; ++j) {
            float bv = cur_l;
            int   bidx = lane;
#pragma unroll
            for (int s = 1; s < 64; s <<= 1) {
                float ov = __shfl_xor(bv, s, 64);
                int   oi = __shfl_xor(bidx, s, 64);
                bool take = (ov > bv) || (ov == bv && oi < bidx);
                if (take) { bv = ov; bidx = oi; }
            }
            if (lane == j) { selv = bv; selidx = bidx; }
            if (lane == bidx) cur_l = -INFINITY;
        }

        float out_logit = __shfl(vub, selidx, 64);
        int   out_idx   = selidx;

        // adjacent-gap check on the sorted biased values (lanes 0..8)
        float nxtv = __shfl_down(selv, 1, 64);
        bool  bad  = (lane < TOPK) && (selv - nxtv < EPS_GAP);
        if (__any(bad)) {
            // exact f64 recompute, ~25 tokens total; unrolled so 16 loads in flight
            const float4* xrow = (const float4*)(x + (size_t)(t0 + t) * DIM);
            double d0 = 0.0, d1 = 0.0;
#pragma unroll 8
            for (int k4 = 0; k4 < DIM / 4; ++k4) {
                float4 wv = wt4[k4 * 64 + lane];
                float4 xv = xrow[k4];
                d0 = fma((double)xv.x, (double)wv.x, d0);
                d1 = fma((double)xv.y, (double)wv.y, d1);
                d0 = fma((double)xv.z, (double)wv.z, d0);
                d1 = fma((double)xv.w, (double)wv.w, d1);
            }
            const double dvub = (d0 + d1) + (double)b_lane;
            const float  vubf = (float)dvub;
            double dcur = dvub + (double)bi_lane;
#pragma unroll
            for (int j = 0; j < TOPK; ++j) {
                double bv = dcur;
                int    bidx = lane;
#pragma unroll
                for (int s = 1; s < 64; s <<= 1) {
                    double ov = __shfl_xor(bv, s, 64);
                    int    oi = __shfl_xor(bidx, s, 64);
                    bool take = (ov > bv) || (ov == bv && oi < bidx);
                    if (take) { bv = ov; bidx = oi; }
                }
                float wub = __shfl(vubf, bidx, 64);
                if (lane == j) { out_logit = wub; out_idx = bidx; }
                if (lane == bidx) dcur = -(double)INFINITY;
            }
        }

        // softmax over lanes 0..7 (xor 1,2,4 stays within the 8-group)
        float sv = (lane < TOPK) ? out_logit : -INFINITY;
        float m = sv;
        m = fmaxf(m, __shfl_xor(m, 1, 64));
        m = fmaxf(m, __shfl_xor(m, 2, 64));
        m = fmaxf(m, __shfl_xor(m, 4, 64));
        float e = (lane < TOPK) ? expf(sv - m) : 0.f;
        float ssum = e;
        ssum += __shfl_xor(ssum, 1, 64);
        ssum += __shfl_xor(ssum, 2, 64);
        ssum += __shfl_xor(ssum, 4, 64);

        const int tt = t0 + t;
        if (lane < TOPK) {
            float p = e / ssum;
            float r = rand_u[tt * TOPK + lane];
            out[tt * TOPK + lane] = (r > FILTER_R) ? p : 0.f;
            out[TOKENS * TOPK + tt * TOPK + lane] = (float)out_idx;
            atomicAdd(&lds_hist[out_idx], 1);
        }
    }

    __syncthreads();
    if (threadIdx.x < NEXP) atomicAdd(&hist_g[threadIdx.x], lds_hist[threadIdx.x]);
}

__global__ void bias_update_kernel(const float* __restrict__ bi,
                                   const int* __restrict__ hist,
                                   float* __restrict__ out_bi) {
    int e = threadIdx.x;
    float c_avg = (float)TOKENS / (float)NEXP;     // 256
    float e_i = c_avg - (float)hist[e];
    float s = (e_i > 0.f) ? 1.f : ((e_i < 0.f) ? -1.f : 0.f);
    out_bi[e] = bi[e] + LOAD_LR * s;
}

extern "C" void kernel_launch(void* const* d_in, const int* in_sizes, int n_in,
                              void* d_out, int out_size, void* d_ws, size_t ws_size,
                              hipStream_t stream) {
    const float* x      = (const float*)d_in[0];
    const float* W      = (const float*)d_in[1];
    const float* b      = (const float*)d_in[2];
    const float* bi     = (const float*)d_in[3];
    const float* rand_u = (const float*)d_in[4];

    float* out  = (float*)d_out;
    float* wt4  = (float*)d_ws;
    int*   hist = (int*)((char*)d_ws + (size_t)DIM * NEXP * sizeof(float));

    wt_transpose_kernel<<<(DIM * NEXP) / 256, 256, 0, stream>>>(W, wt4, hist);

    router_kernel<<<TOKENS / TB, 256, 0, stream>>>(
        x, b, bi, rand_u, (const float4*)wt4, out, hist);

    bias_update_kernel<<<1, NEXP, 0, stream>>>(bi, hist, out + 2 * TOKENS * TOPK);
}